// Round 4
// baseline (84823.761 us; speedup 1.0000x reference)
//
#include <hip/hip_runtime.h>

static constexpr int B_ = 8;
static constexpr int C_ = 64;
static constexpr int H_ = 256;
static constexpr int W_ = 512;
static constexpr int K_ = 9;
static constexpr int PAD_ = 4;

static constexpr int TILE_ = 256;             // columns per block tile
static constexpr int TW_ = TILE_ + 2 * PAD_;  // 264 staged floats per row
static constexpr int TW4_ = TW_ / 4;          // 66 float4 per staged row
static constexpr int CIH_ = 32;               // input channels per staging half

// Device-wide barrier: monotonic counter, one atomic per block.
// Mirrors cooperative_groups grid.sync semantics (fence/sync/atomic/spin).
__device__ __forceinline__ void grid_sync_dev(unsigned* cnt, unsigned target) {
    __threadfence();  // release: this block's row writes visible device-wide
    __syncthreads();
    if (threadIdx.x == 0) {
        __hip_atomic_fetch_add(cnt, 1u, __ATOMIC_RELEASE,
                               __HIP_MEMORY_SCOPE_AGENT);
        while (__hip_atomic_load(cnt, __ATOMIC_ACQUIRE,
                                 __HIP_MEMORY_SCOPE_AGENT) < target)
            __builtin_amdgcn_s_sleep(1);
    }
    __syncthreads();
    __threadfence();  // acquire for all lanes' subsequent reads
}

// Persistent directional scan: buf[row i] += relu(conv1d(buf[row i-dir]) + b),
// numSteps sequential steps with a device barrier between steps.
// gridDim.x MUST be 256 (1 block/CU co-residency by LDS: 34 KB -> 4/CU cap).
// blockDim.x = 256 (UD/DU) or 128 (LR/RL).
// Wave = one c_out (wave-uniform -> s_load weights); lane = 4 adjacent cols.
// LDS: 32-ci half staged at a time (2 halves per step) -> 33792 B static.
// Block->(batch,tile,cog) mapping keeps each batch's blocks on one XCD, so
// all producer->consumer row sharing is intra-XCD; only the barrier counter
// crosses XCDs (device-scope atomic).
__global__ __launch_bounds__(256) void scan_dir_kernel(
    float* __restrict__ buf, const float* __restrict__ w,
    const float* __restrict__ bias,
    const int N, const long long rowStride, const long long colStride,
    const long long chanStride, const int startRow, const int rowDir,
    const int numSteps, unsigned* cnt)
{
    __shared__ float4 s_in4[CIH_ * TW4_];  // 33792 bytes

    const int tid = threadIdx.x;
    const int lane = tid & 63;
    const int waveId = tid >> 6;
    const int coPerBlock = blockDim.x >> 6;   // 4 or 2
    const int ncog = C_ / coPerBlock;         // 16 or 32
    const int ntiles = N >> 8;                // 2 (N=512) or 1 (N=256)

    const int xcd = blockIdx.x & 7;
    const int slot = blockIdx.x >> 3;         // 0..31
    const int ptl = slot / ncog;              // 0..ntiles-1
    const int cog = slot - ptl * ncog;
    const int pt = xcd * ntiles + ptl;        // 0..8*ntiles-1
    const int b = pt / ntiles;
    const int tile = pt - b * ntiles;
    const int tile0 = tile << 8;
    const int co = __builtin_amdgcn_readfirstlane(cog * coPerBlock + waveId);

    const long long base = (long long)b * C_ * chanStride;
    const float* wco = w + co * (C_ * K_);
    const float bco = bias[co];

    for (int s = 0; s < numSteps; ++s) {
        const int irow = startRow + s * rowDir;
        const long long prow = base + (long long)(irow - rowDir) * rowStride;
        // output row for THIS wave's channel co:
        const long long orowc = base + (long long)co * chanStride +
                                (long long)irow * rowStride;
        const int col0 = tile0 + lane * 4;

        // Early RMW load: row irow (channel co) is untouched by this
        // direction until now -> safe to issue before compute (hides lat).
        float4 cur;
        if (colStride == 1) cur = *(const float4*)(buf + orowc + col0);

        float a0 = 0.f, a1 = 0.f, a2 = 0.f, a3 = 0.f;

        for (int half = 0; half < 2; ++half) {
            // ---- stage ci in [half*32, half*32+32), cols tile0-4..tile0+259
            if (colStride == 1) {
                for (int idx = tid; idx < CIH_ * TW4_; idx += blockDim.x) {
                    const int ci = idx / TW4_;
                    const int j = idx - ci * TW4_;
                    const int g0 = tile0 + j * 4 - PAD_;
                    const float* src =
                        buf + prow + (long long)(half * CIH_ + ci) * chanStride;
                    float4 v;
                    if (g0 >= 0 && g0 + 3 < N) {
                        v = *(const float4*)(src + g0);
                    } else {
                        v.x = (g0 + 0 >= 0 && g0 + 0 < N) ? src[g0 + 0] : 0.f;
                        v.y = (g0 + 1 >= 0 && g0 + 1 < N) ? src[g0 + 1] : 0.f;
                        v.z = (g0 + 2 >= 0 && g0 + 2 < N) ? src[g0 + 2] : 0.f;
                        v.w = (g0 + 3 >= 0 && g0 + 3 < N) ? src[g0 + 3] : 0.f;
                    }
                    s_in4[idx] = v;
                }
            } else {
                float* sf = (float*)s_in4;
                for (int idx = tid; idx < CIH_ * TW_; idx += blockDim.x) {
                    const int ci = idx / TW_;
                    const int cc = idx - ci * TW_;
                    const int g = tile0 + cc - PAD_;
                    float v = 0.f;
                    if (g >= 0 && g < N)
                        v = buf[prow +
                                (long long)(half * CIH_ + ci) * chanStride +
                                (long long)g * colStride];
                    sf[idx] = v;
                }
            }
            __syncthreads();

            // ---- accumulate 32 ci: 3 x ds_read_b128 + 36 fma per ci,
            //      next-ci LDS reads prefetched under the FMAs
            const float* wh = wco + (half * CIH_) * K_;
            float4 f0 = s_in4[lane];
            float4 f1 = s_in4[lane + 1];
            float4 f2 = s_in4[lane + 2];
            for (int ci = 0; ci < CIH_; ++ci) {
                float4 p0 = f0, p1 = f1, p2 = f2;
                if (ci + 1 < CIH_) {
                    p0 = s_in4[(ci + 1) * TW4_ + lane];
                    p1 = s_in4[(ci + 1) * TW4_ + lane + 1];
                    p2 = s_in4[(ci + 1) * TW4_ + lane + 2];
                }
                const float x[12] = {f0.x, f0.y, f0.z, f0.w, f1.x, f1.y,
                                     f1.z, f1.w, f2.x, f2.y, f2.z, f2.w};
                const float* wr = wh + ci * K_;  // wave-uniform -> s_load
#pragma unroll
                for (int k = 0; k < K_; ++k) {
                    const float wk = wr[k];
                    a0 = fmaf(wk, x[k + 0], a0);
                    a1 = fmaf(wk, x[k + 1], a1);
                    a2 = fmaf(wk, x[k + 2], a2);
                    a3 = fmaf(wk, x[k + 3], a3);
                }
                f0 = p0; f1 = p1; f2 = p2;
            }
            __syncthreads();  // done reading before next half overwrites LDS
        }

        // ---- buf[co, irow] += relu(acc + bias)
        if (colStride == 1) {
            float4* dst = (float4*)(buf + orowc + col0);
            cur.x += fmaxf(a0 + bco, 0.f);
            cur.y += fmaxf(a1 + bco, 0.f);
            cur.z += fmaxf(a2 + bco, 0.f);
            cur.w += fmaxf(a3 + bco, 0.f);
            *dst = cur;
        } else {
            float* d0 = buf + orowc + (long long)(col0 + 0) * colStride;
            float* d1 = buf + orowc + (long long)(col0 + 1) * colStride;
            float* d2 = buf + orowc + (long long)(col0 + 2) * colStride;
            float* d3 = buf + orowc + (long long)(col0 + 3) * colStride;
            *d0 += fmaxf(a0 + bco, 0.f);
            *d1 += fmaxf(a1 + bco, 0.f);
            *d2 += fmaxf(a2 + bco, 0.f);
            *d3 += fmaxf(a3 + bco, 0.f);
        }

        if (s != numSteps - 1)
            grid_sync_dev(cnt, (unsigned)(s + 1) * gridDim.x);
    }
}

// out[b,c,s,r] = in[b,c,r,s] for each of the B*C planes.
__global__ __launch_bounds__(256) void transpose_kernel(
    const float* __restrict__ in, float* __restrict__ out,
    const int R, const int S)
{
    __shared__ float tile[32][33];
    const size_t plane = (size_t)blockIdx.z * R * S;
    const int s0 = blockIdx.x * 32;
    const int r0 = blockIdx.y * 32;
    const int tx = threadIdx.x;
    const int ty = threadIdx.y;
#pragma unroll
    for (int j = 0; j < 32; j += 8)
        tile[ty + j][tx] = in[plane + (size_t)(r0 + ty + j) * S + s0 + tx];
    __syncthreads();
#pragma unroll
    for (int j = 0; j < 32; j += 8)
        out[plane + (size_t)(s0 + ty + j) * R + r0 + tx] = tile[tx][ty + j];
}

static void launch_scan(float* buf, const float* w, const float* bias,
                        int N, long long rowStride, long long colStride,
                        long long chanStride, int startRow, int rowDir,
                        int numSteps, unsigned* cnt, int nthreads,
                        bool persistent, hipStream_t stream)
{
    if (persistent) {
        scan_dir_kernel<<<256, nthreads, 0, stream>>>(
            buf, w, bias, N, rowStride, colStride, chanStride, startRow,
            rowDir, numSteps, cnt);
    } else {
        for (int s = 0; s < numSteps; ++s)
            scan_dir_kernel<<<256, nthreads, 0, stream>>>(
                buf, w, bias, N, rowStride, colStride, chanStride,
                startRow + s * rowDir, rowDir, 1, nullptr);
    }
}

extern "C" void kernel_launch(void* const* d_in, const int* in_sizes, int n_in,
                              void* d_out, int out_size, void* d_ws,
                              size_t ws_size, hipStream_t stream)
{
    const float* x    = (const float*)d_in[0];
    const float* w_ud = (const float*)d_in[1];
    const float* b_ud = (const float*)d_in[2];
    const float* w_du = (const float*)d_in[3];
    const float* b_du = (const float*)d_in[4];
    const float* w_lr = (const float*)d_in[5];
    const float* b_lr = (const float*)d_in[6];
    const float* w_rl = (const float*)d_in[7];
    const float* b_rl = (const float*)d_in[8];
    float* out = (float*)d_out;

    const size_t total = (size_t)B_ * C_ * H_ * W_;
    const long long chan = (long long)H_ * W_;

    const bool haveCnt = ws_size >= 256;
    const bool haveT = ws_size >= 256 + total * sizeof(float);
    unsigned* cnt = (unsigned*)d_ws;                 // 4 counters, 64 B apart
    float* wsT = (float*)((char*)d_ws + 256);

    hipMemcpyAsync(out, x, total * sizeof(float), hipMemcpyDeviceToDevice,
                   stream);
    if (haveCnt) hipMemsetAsync(d_ws, 0, 256, stream);

    // ---- up->down / down->up: conv along w (contiguous), scan over h ----
    launch_scan(out, w_ud, b_ud, W_, (long long)W_, 1LL, chan,
                1, +1, H_ - 1, cnt + 0, 256, haveCnt, stream);
    launch_scan(out, w_du, b_du, W_, (long long)W_, 1LL, chan,
                H_ - 2, -1, H_ - 1, cnt + 16, 256, haveCnt, stream);

    if (haveT) {
        // transpose [b,c,h,w] -> [b,c,w,h]; conv along h becomes contiguous
        {
            dim3 gt(W_ / 32, H_ / 32, B_ * C_);
            transpose_kernel<<<gt, dim3(32, 8), 0, stream>>>(out, wsT, H_, W_);
        }
        launch_scan(wsT, w_lr, b_lr, H_, (long long)H_, 1LL, chan,
                    1, +1, W_ - 1, cnt + 32, 128, haveCnt, stream);
        launch_scan(wsT, w_rl, b_rl, H_, (long long)H_, 1LL, chan,
                    W_ - 2, -1, W_ - 1, cnt + 48, 128, haveCnt, stream);
        {
            dim3 gt(H_ / 32, W_ / 32, B_ * C_);
            transpose_kernel<<<gt, dim3(32, 8), 0, stream>>>(wsT, out, W_, H_);
        }
    } else {
        // strided fallback directly on out: cols = h (stride W), rows = w
        launch_scan(out, w_lr, b_lr, H_, 1LL, (long long)W_, chan,
                    1, +1, W_ - 1, cnt + 32, 128, haveCnt, stream);
        launch_scan(out, w_rl, b_rl, H_, 1LL, (long long)W_, chan,
                    W_ - 2, -1, W_ - 1, cnt + 48, 128, haveCnt, stream);
    }
}

// Round 5
// 60810.724 us; speedup vs baseline: 1.3949x; 1.3949x over previous
//
#include <hip/hip_runtime.h>

static constexpr int B_ = 8;
static constexpr int C_ = 64;
static constexpr int H_ = 256;
static constexpr int W_ = 512;
static constexpr int K_ = 9;
static constexpr int PAD_ = 4;

static constexpr int TILE_ = 256;             // columns per block tile
static constexpr int TW_ = TILE_ + 2 * PAD_;  // 264 staged floats per row
static constexpr int TW4_ = TW_ / 4;          // 66 float4 per staged row
static constexpr int CIH_ = 32;               // input channels per staging half

// Counter layout in d_ws: 4 directions x 8 batches x 256 B.
static constexpr int CNT_BATCH_STRIDE_U32 = 64;   // 256 B
static constexpr int CNT_DIR_STRIDE_U32 = 512;    // 2 KB
static constexpr int CNT_BYTES = 8192;

// Per-batch device barrier. Release/acquire fences ONCE per call; the poll
// uses RELAXED agent-scope atomic loads (sc1 coherence-point access, no
// buffer_inv per iteration — the round-4 ACQUIRE poll emitted cache
// invalidation every spin and cost ~50us/step).
__device__ __forceinline__ void batch_sync_dev(unsigned* cnt, unsigned target) {
    __threadfence();  // release: this block's row writes visible device-wide
    __syncthreads();
    if (threadIdx.x == 0) {
        __hip_atomic_fetch_add(cnt, 1u, __ATOMIC_RELAXED,
                               __HIP_MEMORY_SCOPE_AGENT);
        while (__hip_atomic_load(cnt, __ATOMIC_RELAXED,
                                 __HIP_MEMORY_SCOPE_AGENT) < target)
            __builtin_amdgcn_s_sleep(2);
    }
    __syncthreads();
    __threadfence();  // acquire: subsequent reads see other blocks' writes
}

// Persistent directional scan: buf[row i] += relu(conv1d(buf[row i-dir]) + b),
// numSteps sequential steps with a per-batch device barrier between steps.
// gridDim.x MUST be 256 (1 block/CU co-residency; 34 KB LDS, <=4 waves).
// blockDim.x = 256 (UD/DU) or 128 (LR/RL).
// Wave = one c_out (wave-uniform -> s_load weights); lane = 4 adjacent cols.
// LDS: 32-ci half staged at a time (2 halves per step) -> 33792 B static.
// Block->(batch,tile,cog) mapping keeps each batch's blocks on one XCD
// (perf-only assumption; correctness comes from device-scope fences).
__global__ __launch_bounds__(256) void scan_dir_kernel(
    float* __restrict__ buf, const float* __restrict__ w,
    const float* __restrict__ bias,
    const int N, const long long rowStride, const long long colStride,
    const long long chanStride, const int startRow, const int rowDir,
    const int numSteps, unsigned* cnt)
{
    __shared__ float4 s_in4[CIH_ * TW4_];  // 33792 bytes

    const int tid = threadIdx.x;
    const int lane = tid & 63;
    const int waveId = tid >> 6;
    const int coPerBlock = blockDim.x >> 6;   // 4 or 2
    const int ncog = C_ / coPerBlock;         // 16 or 32
    const int ntiles = N >> 8;                // 2 (N=512) or 1 (N=256)
    const int bpb = ncog * ntiles;            // blocks per batch = 32

    const int xcd = blockIdx.x & 7;
    const int slot = blockIdx.x >> 3;         // 0..31
    const int ptl = slot / ncog;              // 0..ntiles-1
    const int cog = slot - ptl * ncog;
    const int pt = xcd * ntiles + ptl;        // 0..8*ntiles-1
    const int b = pt / ntiles;
    const int tile = pt - b * ntiles;
    const int tile0 = tile << 8;
    const int co = __builtin_amdgcn_readfirstlane(cog * coPerBlock + waveId);

    unsigned* mycnt = cnt ? cnt + b * CNT_BATCH_STRIDE_U32 : nullptr;

    const long long base = (long long)b * C_ * chanStride;
    const float* wco = w + co * (C_ * K_);
    const float bco = bias[co];

    for (int s = 0; s < numSteps; ++s) {
        const int irow = startRow + s * rowDir;
        const long long prow = base + (long long)(irow - rowDir) * rowStride;
        // output row for THIS wave's channel co:
        const long long orowc = base + (long long)co * chanStride +
                                (long long)irow * rowStride;
        const int col0 = tile0 + lane * 4;

        // Early RMW load: row irow (channel co) is untouched by this
        // direction until now -> safe to issue before compute (hides lat).
        float4 cur;
        if (colStride == 1) cur = *(const float4*)(buf + orowc + col0);

        float a0 = 0.f, a1 = 0.f, a2 = 0.f, a3 = 0.f;

        for (int half = 0; half < 2; ++half) {
            // ---- stage ci in [half*32, half*32+32), cols tile0-4..tile0+259
            if (colStride == 1) {
                for (int idx = tid; idx < CIH_ * TW4_; idx += blockDim.x) {
                    const int ci = idx / TW4_;
                    const int j = idx - ci * TW4_;
                    const int g0 = tile0 + j * 4 - PAD_;
                    const float* src =
                        buf + prow + (long long)(half * CIH_ + ci) * chanStride;
                    float4 v;
                    if (g0 >= 0 && g0 + 3 < N) {
                        v = *(const float4*)(src + g0);
                    } else {
                        v.x = (g0 + 0 >= 0 && g0 + 0 < N) ? src[g0 + 0] : 0.f;
                        v.y = (g0 + 1 >= 0 && g0 + 1 < N) ? src[g0 + 1] : 0.f;
                        v.z = (g0 + 2 >= 0 && g0 + 2 < N) ? src[g0 + 2] : 0.f;
                        v.w = (g0 + 3 >= 0 && g0 + 3 < N) ? src[g0 + 3] : 0.f;
                    }
                    s_in4[idx] = v;
                }
            } else {
                float* sf = (float*)s_in4;
                for (int idx = tid; idx < CIH_ * TW_; idx += blockDim.x) {
                    const int ci = idx / TW_;
                    const int cc = idx - ci * TW_;
                    const int g = tile0 + cc - PAD_;
                    float v = 0.f;
                    if (g >= 0 && g < N)
                        v = buf[prow +
                                (long long)(half * CIH_ + ci) * chanStride +
                                (long long)g * colStride];
                    sf[idx] = v;
                }
            }
            __syncthreads();

            // ---- accumulate 32 ci: 3 x ds_read_b128 + 36 fma per ci,
            //      next-ci LDS reads prefetched under the FMAs
            const float* wh = wco + (half * CIH_) * K_;
            float4 f0 = s_in4[lane];
            float4 f1 = s_in4[lane + 1];
            float4 f2 = s_in4[lane + 2];
            for (int ci = 0; ci < CIH_; ++ci) {
                float4 p0 = f0, p1 = f1, p2 = f2;
                if (ci + 1 < CIH_) {
                    p0 = s_in4[(ci + 1) * TW4_ + lane];
                    p1 = s_in4[(ci + 1) * TW4_ + lane + 1];
                    p2 = s_in4[(ci + 1) * TW4_ + lane + 2];
                }
                const float x[12] = {f0.x, f0.y, f0.z, f0.w, f1.x, f1.y,
                                     f1.z, f1.w, f2.x, f2.y, f2.z, f2.w};
                const float* wr = wh + ci * K_;  // wave-uniform -> s_load
#pragma unroll
                for (int k = 0; k < K_; ++k) {
                    const float wk = wr[k];
                    a0 = fmaf(wk, x[k + 0], a0);
                    a1 = fmaf(wk, x[k + 1], a1);
                    a2 = fmaf(wk, x[k + 2], a2);
                    a3 = fmaf(wk, x[k + 3], a3);
                }
                f0 = p0; f1 = p1; f2 = p2;
            }
            __syncthreads();  // done reading before next half overwrites LDS
        }

        // ---- buf[co, irow] += relu(acc + bias)
        if (colStride == 1) {
            float4* dst = (float4*)(buf + orowc + col0);
            cur.x += fmaxf(a0 + bco, 0.f);
            cur.y += fmaxf(a1 + bco, 0.f);
            cur.z += fmaxf(a2 + bco, 0.f);
            cur.w += fmaxf(a3 + bco, 0.f);
            *dst = cur;
        } else {
            float* d0 = buf + orowc + (long long)(col0 + 0) * colStride;
            float* d1 = buf + orowc + (long long)(col0 + 1) * colStride;
            float* d2 = buf + orowc + (long long)(col0 + 2) * colStride;
            float* d3 = buf + orowc + (long long)(col0 + 3) * colStride;
            *d0 += fmaxf(a0 + bco, 0.f);
            *d1 += fmaxf(a1 + bco, 0.f);
            *d2 += fmaxf(a2 + bco, 0.f);
            *d3 += fmaxf(a3 + bco, 0.f);
        }

        if (s != numSteps - 1)
            batch_sync_dev(mycnt, (unsigned)((s + 1) * bpb));
    }
}

// out[b,c,s,r] = in[b,c,r,s] for each of the B*C planes.
__global__ __launch_bounds__(256) void transpose_kernel(
    const float* __restrict__ in, float* __restrict__ out,
    const int R, const int S)
{
    __shared__ float tile[32][33];
    const size_t plane = (size_t)blockIdx.z * R * S;
    const int s0 = blockIdx.x * 32;
    const int r0 = blockIdx.y * 32;
    const int tx = threadIdx.x;
    const int ty = threadIdx.y;
#pragma unroll
    for (int j = 0; j < 32; j += 8)
        tile[ty + j][tx] = in[plane + (size_t)(r0 + ty + j) * S + s0 + tx];
    __syncthreads();
#pragma unroll
    for (int j = 0; j < 32; j += 8)
        out[plane + (size_t)(s0 + ty + j) * R + r0 + tx] = tile[tx][ty + j];
}

static void launch_scan(float* buf, const float* w, const float* bias,
                        int N, long long rowStride, long long colStride,
                        long long chanStride, int startRow, int rowDir,
                        int numSteps, unsigned* cnt, int nthreads,
                        bool persistent, hipStream_t stream)
{
    if (persistent) {
        scan_dir_kernel<<<256, nthreads, 0, stream>>>(
            buf, w, bias, N, rowStride, colStride, chanStride, startRow,
            rowDir, numSteps, cnt);
    } else {
        for (int s = 0; s < numSteps; ++s)
            scan_dir_kernel<<<256, nthreads, 0, stream>>>(
                buf, w, bias, N, rowStride, colStride, chanStride,
                startRow + s * rowDir, rowDir, 1, nullptr);
    }
}

extern "C" void kernel_launch(void* const* d_in, const int* in_sizes, int n_in,
                              void* d_out, int out_size, void* d_ws,
                              size_t ws_size, hipStream_t stream)
{
    const float* x    = (const float*)d_in[0];
    const float* w_ud = (const float*)d_in[1];
    const float* b_ud = (const float*)d_in[2];
    const float* w_du = (const float*)d_in[3];
    const float* b_du = (const float*)d_in[4];
    const float* w_lr = (const float*)d_in[5];
    const float* b_lr = (const float*)d_in[6];
    const float* w_rl = (const float*)d_in[7];
    const float* b_rl = (const float*)d_in[8];
    float* out = (float*)d_out;

    const size_t total = (size_t)B_ * C_ * H_ * W_;
    const long long chan = (long long)H_ * W_;

    const bool haveCnt = ws_size >= (size_t)CNT_BYTES;
    const bool haveT = ws_size >= (size_t)CNT_BYTES + total * sizeof(float);
    unsigned* cnt = (unsigned*)d_ws;
    float* wsT = (float*)((char*)d_ws + CNT_BYTES);

    hipMemcpyAsync(out, x, total * sizeof(float), hipMemcpyDeviceToDevice,
                   stream);
    if (haveCnt) hipMemsetAsync(d_ws, 0, CNT_BYTES, stream);

    // ---- up->down / down->up: conv along w (contiguous), scan over h ----
    launch_scan(out, w_ud, b_ud, W_, (long long)W_, 1LL, chan,
                1, +1, H_ - 1, cnt + 0 * CNT_DIR_STRIDE_U32, 256, haveCnt,
                stream);
    launch_scan(out, w_du, b_du, W_, (long long)W_, 1LL, chan,
                H_ - 2, -1, H_ - 1, cnt + 1 * CNT_DIR_STRIDE_U32, 256, haveCnt,
                stream);

    if (haveT) {
        // transpose [b,c,h,w] -> [b,c,w,h]; conv along h becomes contiguous
        {
            dim3 gt(W_ / 32, H_ / 32, B_ * C_);
            transpose_kernel<<<gt, dim3(32, 8), 0, stream>>>(out, wsT, H_, W_);
        }
        launch_scan(wsT, w_lr, b_lr, H_, (long long)H_, 1LL, chan,
                    1, +1, W_ - 1, cnt + 2 * CNT_DIR_STRIDE_U32, 128, haveCnt,
                    stream);
        launch_scan(wsT, w_rl, b_rl, H_, (long long)H_, 1LL, chan,
                    W_ - 2, -1, W_ - 1, cnt + 3 * CNT_DIR_STRIDE_U32, 128,
                    haveCnt, stream);
        {
            dim3 gt(H_ / 32, W_ / 32, B_ * C_);
            transpose_kernel<<<gt, dim3(32, 8), 0, stream>>>(wsT, out, W_, H_);
        }
    } else {
        // strided fallback directly on out: cols = h (stride W), rows = w
        launch_scan(out, w_lr, b_lr, H_, 1LL, (long long)W_, chan,
                    1, +1, W_ - 1, cnt + 2 * CNT_DIR_STRIDE_U32, 128, haveCnt,
                    stream);
        launch_scan(out, w_rl, b_rl, H_, 1LL, (long long)W_, chan,
                    W_ - 2, -1, W_ - 1, cnt + 3 * CNT_DIR_STRIDE_U32, 128,
                    haveCnt, stream);
    }
}

// Round 6
// 20463.803 us; speedup vs baseline: 4.1451x; 2.9716x over previous
//
#include <hip/hip_runtime.h>

static constexpr int B_ = 8;
static constexpr int C_ = 64;
static constexpr int H_ = 256;
static constexpr int W_ = 512;
static constexpr int K_ = 9;
static constexpr int PAD_ = 4;

// workspace layout (bytes)
static constexpr size_t FLAGS_OFF = 0;                  // 4 dirs x 256 blks x 64 B
static constexpr size_t FLAGS_PER_DIR = 256 * 64;      // 16 KB
static constexpr size_t FLAGS_BYTES = 4 * FLAGS_PER_DIR;
static constexpr size_t HALO_OFF = 1ull << 20;          // 1 MB
static constexpr size_t HALO_PER_DIR = 2ull << 20;      // 2 MB
static constexpr size_t TBUF_OFF = 16ull << 20;         // 16 MB

// IC-coherent (agent-scope) accesses: performed at the coherence point, so no
// L2 fences are needed anywhere. Relaxed = no buffer_inv/buffer_wbl2 emitted.
__device__ __forceinline__ void ic_store(float* p, float v) {
    (void)__hip_atomic_exchange((unsigned*)p, __float_as_uint(v),
                                __ATOMIC_RELAXED, __HIP_MEMORY_SCOPE_AGENT);
}
__device__ __forceinline__ float ic_load(const float* p) {
    unsigned u = __hip_atomic_load((const unsigned*)p, __ATOMIC_RELAXED,
                                   __HIP_MEMORY_SCOPE_AGENT);
    return __uint_as_float(u);
}

// Persistent directional scan, fence-free.
// Block = ALL 64 channels x T columns of one batch. Carry row lives in LDS
// across steps; only 4-col halos cross blocks (atomics via IC + flag counters).
// Thread t: co = t>>2 (output channel), g = t&3 (ci-quarter, ci = g+4i).
// Per thread: 16ci x 9k weights in VGPRs (loaded once), partial conv over its
// ci-quarter for all T cols, then 2-round shfl_xor butterfly over g.
// Producer release: halo atomic-swaps -> s_waitcnt vmcnt(0) -> barrier ->
// relaxed flag add. Consumer: relaxed flag spin -> atomic halo loads. Parity
// double-buffered halo slots; neighbor skew is <=1 so 2 slots suffice.
template <int T>
__global__ __launch_bounds__(256, 2) void scan_halo_kernel(
    float* __restrict__ buf, const float* __restrict__ w,
    const float* __restrict__ bias, const int N,
    const long long rowStride, const long long colStride,
    const long long chanStride, const int startRow, const int rowDir,
    const int numSteps, unsigned* __restrict__ flags,
    float* __restrict__ halo)
{
    constexpr int CPT = T / 4;   // output cols per thread
    constexpr int WIN = T + 8;   // staged window per ci
    __shared__ float prev[C_][WIN];

    const int tid = threadIdx.x;
    const int co = tid >> 2;
    const int g = tid & 3;
    const int TPB = N / T;
    const int blk = blockIdx.x;
    const int tile = blk % TPB;
    const int b = blk / TPB;
    const int t0 = tile * T;
    const bool hasL = tile > 0;
    const bool hasR = tile < TPB - 1;

    const long long base = (long long)b * C_ * chanStride;

    // one-time: weights w[co][ci=g+4i][k] -> 144 VGPRs
    float wreg[16][K_];
    {
        const float* wb = w + (long long)co * C_ * K_;
#pragma unroll
        for (int i = 0; i < 16; ++i)
#pragma unroll
            for (int k = 0; k < K_; ++k)
                wreg[i][k] = wb[(g + 4 * i) * K_ + k];
    }
    const float bco = bias[co];

    for (int s = 0; s < numSteps; ++s) {
        const int irow = startRow + s * rowDir;

        if (s == 0) {
            // stage carry row from global (prev kernel's output, incl. halo)
            const long long pr = base + (long long)(irow - rowDir) * rowStride;
            for (int idx = tid; idx < C_ * WIN; idx += 256) {
                const int ci = idx / WIN, j = idx - ci * WIN;
                const int gc = t0 + j - PAD_;
                float v = 0.f;
                if (gc >= 0 && gc < N)
                    v = buf[pr + (long long)ci * chanStride +
                            (long long)gc * colStride];
                prev[ci][j] = v;
            }
        } else {
            // wait for neighbors' step s-1 (two waves spin in parallel)
            if (tid == 0 && hasL) {
                while (__hip_atomic_load(flags + (blk - 1) * 16,
                                         __ATOMIC_RELAXED,
                                         __HIP_MEMORY_SCOPE_AGENT) <
                       (unsigned)s)
                    __builtin_amdgcn_s_sleep(1);
            }
            if (tid == 64 && hasR) {
                while (__hip_atomic_load(flags + (blk + 1) * 16,
                                         __ATOMIC_RELAXED,
                                         __HIP_MEMORY_SCOPE_AGENT) <
                       (unsigned)s)
                    __builtin_amdgcn_s_sleep(1);
            }
            __syncthreads();
            // import halos (thread t -> ci = t>>2, c = t&3)
            const int par = (s - 1) & 1;
            float lv = 0.f, rv = 0.f;
            if (hasL)
                lv = ic_load(halo + (((blk - 1) * 2 + par) * 2 + 1) * 256 + tid);
            if (hasR)
                rv = ic_load(halo + (((blk + 1) * 2 + par) * 2 + 0) * 256 + tid);
            prev[tid >> 2][tid & 3] = lv;
            prev[tid >> 2][T + 4 + (tid & 3)] = rv;
        }
        __syncthreads();

        // x (RMW input) — issue early, used after compute
        const long long orow = base + (long long)co * chanStride +
                               (long long)irow * rowStride;
        const int colL = t0 + g * CPT;
        float xv[CPT];
        if (colStride == 1) {
            if constexpr (CPT == 4) {
                const float4 v4 = *(const float4*)(buf + orow + colL);
                xv[0] = v4.x; xv[1] = v4.y; xv[2] = v4.z; xv[3] = v4.w;
            } else {
                const float2 v2 = *(const float2*)(buf + orow + colL);
                xv[0] = v2.x; xv[1] = v2.y;
            }
        } else {
#pragma unroll
            for (int cc = 0; cc < CPT; ++cc)
                xv[cc] = buf[orow + (long long)(colL + cc) * colStride];
        }

        // partial conv over my ci-quarter, all T cols
        float acc[T];
#pragma unroll
        for (int c = 0; c < T; ++c) acc[c] = 0.f;
#pragma unroll
        for (int i = 0; i < 16; ++i) {
            const int ci = g + 4 * i;   // stride-4 ci: conflict-free LDS rows
            float win[WIN];
            const float4* rp = (const float4*)(&prev[ci][0]);
#pragma unroll
            for (int j = 0; j < WIN / 4; ++j) {
                const float4 v = rp[j];
                win[4 * j + 0] = v.x; win[4 * j + 1] = v.y;
                win[4 * j + 2] = v.z; win[4 * j + 3] = v.w;
            }
#pragma unroll
            for (int k = 0; k < K_; ++k)
#pragma unroll
                for (int c = 0; c < T; ++c)
                    acc[c] = fmaf(wreg[i][k], win[c + k], acc[c]);
        }
        // butterfly over g (lane bits 0-1): all 4 siblings end with full sums
#pragma unroll
        for (int c = 0; c < T; ++c) acc[c] += __shfl_xor(acc[c], 1);
#pragma unroll
        for (int c = 0; c < T; ++c) acc[c] += __shfl_xor(acc[c], 2);

        float r[CPT];
#pragma unroll
        for (int cc = 0; cc < CPT; ++cc)
            r[cc] = xv[cc] + fmaxf(acc[g * CPT + cc] + bco, 0.f);

        // store output row (ordinary cached stores; only this block re-reads
        // these columns, and it does so from LDS)
        if (colStride == 1) {
            if constexpr (CPT == 4) {
                const float4 v4 = {r[0], r[1], r[2], r[3]};
                *(float4*)(buf + orow + colL) = v4;
            } else {
                const float2 v2 = {r[0], r[1]};
                *(float2*)(buf + orow + colL) = v2;
            }
        } else {
#pragma unroll
            for (int cc = 0; cc < CPT; ++cc)
                buf[orow + (long long)(colL + cc) * colStride] = r[cc];
        }

        if (s != numSteps - 1) {
            // export edge cols from regs (parity slot s&1)
            const int par = s & 1;
#pragma unroll
            for (int cc = 0; cc < CPT; ++cc) {
                const int cl = g * CPT + cc;  // local col, compile-time
                if (cl < 4 && hasL)
                    ic_store(halo + ((blk * 2 + par) * 2 + 0) * 256 +
                                 co * 4 + cl,
                             r[cc]);
                if (cl >= T - 4 && hasR)
                    ic_store(halo + ((blk * 2 + par) * 2 + 1) * 256 +
                                 co * 4 + (cl - (T - 4)),
                             r[cc]);
            }
            __syncthreads();  // everyone done READING prev
            // own outputs become next step's carry (interior cols)
#pragma unroll
            for (int cc = 0; cc < CPT; ++cc)
                prev[co][4 + g * CPT + cc] = r[cc];
            // hand-rolled release: my halo swaps are at IC before my flag
            asm volatile("s_waitcnt vmcnt(0)" ::: "memory");
            __syncthreads();
            if (tid == 0)
                __hip_atomic_fetch_add(flags + blk * 16, 1u, __ATOMIC_RELAXED,
                                       __HIP_MEMORY_SCOPE_AGENT);
        }
    }
}

// out[b,c,s,r] = in[b,c,r,s] for each of the B*C planes.
__global__ __launch_bounds__(256) void transpose_kernel(
    const float* __restrict__ in, float* __restrict__ out,
    const int R, const int S)
{
    __shared__ float tile[32][33];
    const size_t plane = (size_t)blockIdx.z * R * S;
    const int s0 = blockIdx.x * 32;
    const int r0 = blockIdx.y * 32;
    const int tx = threadIdx.x;
    const int ty = threadIdx.y;
#pragma unroll
    for (int j = 0; j < 32; j += 8)
        tile[ty + j][tx] = in[plane + (size_t)(r0 + ty + j) * S + s0 + tx];
    __syncthreads();
#pragma unroll
    for (int j = 0; j < 32; j += 8)
        out[plane + (size_t)(s0 + ty + j) * R + r0 + tx] = tile[tx][ty + j];
}

template <int T>
static void launch_dir(float* buf, const float* w, const float* bias, int N,
                       long long rowStride, long long colStride,
                       long long chanStride, int startRow, int rowDir,
                       int numSteps, unsigned* flags, float* halo,
                       bool persistent, hipStream_t stream)
{
    const int nblocks = B_ * (N / T);
    if (persistent) {
        scan_halo_kernel<T><<<nblocks, 256, 0, stream>>>(
            buf, w, bias, N, rowStride, colStride, chanStride, startRow,
            rowDir, numSteps, flags, halo);
    } else {
        for (int s = 0; s < numSteps; ++s)
            scan_halo_kernel<T><<<nblocks, 256, 0, stream>>>(
                buf, w, bias, N, rowStride, colStride, chanStride,
                startRow + s * rowDir, rowDir, 1, nullptr, nullptr);
    }
}

extern "C" void kernel_launch(void* const* d_in, const int* in_sizes, int n_in,
                              void* d_out, int out_size, void* d_ws,
                              size_t ws_size, hipStream_t stream)
{
    const float* x    = (const float*)d_in[0];
    const float* w_ud = (const float*)d_in[1];
    const float* b_ud = (const float*)d_in[2];
    const float* w_du = (const float*)d_in[3];
    const float* b_du = (const float*)d_in[4];
    const float* w_lr = (const float*)d_in[5];
    const float* b_lr = (const float*)d_in[6];
    const float* w_rl = (const float*)d_in[7];
    const float* b_rl = (const float*)d_in[8];
    float* out = (float*)d_out;

    const size_t total = (size_t)B_ * C_ * H_ * W_;
    const long long chan = (long long)H_ * W_;

    const bool haveSync = ws_size >= HALO_OFF + 4 * HALO_PER_DIR;  // 9 MB
    const bool haveT = ws_size >= TBUF_OFF + total * sizeof(float);

    unsigned* flagsBase = (unsigned*)((char*)d_ws + FLAGS_OFF);
    float* haloBase = (float*)((char*)d_ws + HALO_OFF);
    float* wsT = (float*)((char*)d_ws + TBUF_OFF);

    hipMemcpyAsync(out, x, total * sizeof(float), hipMemcpyDeviceToDevice,
                   stream);
    if (haveSync) hipMemsetAsync(d_ws, 0, FLAGS_BYTES, stream);

    unsigned* f0 = flagsBase + 0 * (FLAGS_PER_DIR / 4);
    unsigned* f1 = flagsBase + 1 * (FLAGS_PER_DIR / 4);
    unsigned* f2 = flagsBase + 2 * (FLAGS_PER_DIR / 4);
    unsigned* f3 = flagsBase + 3 * (FLAGS_PER_DIR / 4);
    float* h0 = haloBase + 0 * (HALO_PER_DIR / 4);
    float* h1 = haloBase + 1 * (HALO_PER_DIR / 4);
    float* h2 = haloBase + 2 * (HALO_PER_DIR / 4);
    float* h3 = haloBase + 3 * (HALO_PER_DIR / 4);

    // up->down / down->up on [b,c,h,w]: scan h, conv along w (contig, N=512)
    launch_dir<16>(out, w_ud, b_ud, W_, (long long)W_, 1LL, chan,
                   1, +1, H_ - 1, f0, h0, haveSync, stream);
    launch_dir<16>(out, w_du, b_du, W_, (long long)W_, 1LL, chan,
                   H_ - 2, -1, H_ - 1, f1, h1, haveSync, stream);

    if (haveT) {
        // transpose to [b,c,w,h]: scan w, conv along h (contig, N=256)
        {
            dim3 gt(W_ / 32, H_ / 32, B_ * C_);
            transpose_kernel<<<gt, dim3(32, 8), 0, stream>>>(out, wsT, H_, W_);
        }
        launch_dir<8>(wsT, w_lr, b_lr, H_, (long long)H_, 1LL, chan,
                      1, +1, W_ - 1, f2, h2, haveSync, stream);
        launch_dir<8>(wsT, w_rl, b_rl, H_, (long long)H_, 1LL, chan,
                      W_ - 2, -1, W_ - 1, f3, h3, haveSync, stream);
        {
            dim3 gt(H_ / 32, W_ / 32, B_ * C_);
            transpose_kernel<<<gt, dim3(32, 8), 0, stream>>>(wsT, out, W_, H_);
        }
    } else {
        // strided fallback on [b,c,h,w]: scan w (rowStride=1), conv along h
        launch_dir<8>(out, w_lr, b_lr, H_, 1LL, (long long)W_, chan,
                      1, +1, W_ - 1, f2, h2, haveSync, stream);
        launch_dir<8>(out, w_rl, b_rl, H_, 1LL, (long long)W_, chan,
                      W_ - 2, -1, W_ - 1, f3, h3, haveSync, stream);
    }
}

// Round 7
// 10600.635 us; speedup vs baseline: 8.0018x; 1.9304x over previous
//
#include <hip/hip_runtime.h>

static constexpr int B_ = 8;
static constexpr int C_ = 64;
static constexpr int H_ = 256;
static constexpr int W_ = 512;
static constexpr int K_ = 9;
static constexpr int PAD_ = 4;

// workspace layout (bytes)
static constexpr size_t FLAGS_OFF = 0;                 // 4 dirs x 256 blk x 128 B
static constexpr size_t FLAGS_PER_DIR = 256 * 128;     // 32 KB
static constexpr size_t XCC_OFF = 4 * FLAGS_PER_DIR;   // 128 KB
static constexpr size_t XCC_PER_DIR = 256 * 4;         // 1 KB
static constexpr size_t INIT_BYTES = XCC_OFF + 4 * XCC_PER_DIR;
static constexpr size_t HALO_OFF = 1ull << 20;         // 1 MB
static constexpr size_t HALO_PER_DIR = 1ull << 20;     // 256*2*2*256*4 B = 1 MB
static constexpr size_t TBUF_OFF = 16ull << 20;        // 16 MB

// ---------- agent(IC)-scope ops: proven round-6 path (cross-XCD safe) ------
__device__ __forceinline__ void ic_store_f32(float* p, float v) {
    (void)__hip_atomic_exchange((unsigned*)p, __float_as_uint(v),
                                __ATOMIC_RELAXED, __HIP_MEMORY_SCOPE_AGENT);
}
__device__ __forceinline__ float ic_load_f32(const float* p) {
    unsigned u = __hip_atomic_load((const unsigned*)p, __ATOMIC_RELAXED,
                                   __HIP_MEMORY_SCOPE_AGENT);
    return __uint_as_float(u);
}

// ---------- XCD-L2-scope ops (same-XCD links only; runtime-verified) -------
// Atomics WITHOUT sc1 execute at the issuing XCD's L2: producer and consumer
// on the same XCD are coherent through it, with ~3x lower latency than IC,
// and polls never leave the XCD (no EA/FETCH traffic).
__device__ __forceinline__ unsigned xcc_id() {
    unsigned v;
    asm volatile("s_getreg_b32 %0, hwreg(HW_REG_XCC_ID)" : "=s"(v));
    return v & 0xffu;
}
__device__ __forceinline__ void l2_put_u64(void* p, unsigned long long v) {
    asm volatile("global_atomic_swap_x2 %0, %1, off" :: "v"(p), "v"(v)
                 : "memory");
}
__device__ __forceinline__ void l2_put_u32(void* p, unsigned v) {
    asm volatile("global_atomic_swap %0, %1, off" :: "v"(p), "v"(v)
                 : "memory");
}
__device__ __forceinline__ unsigned l2_get_u32(void* p) {
    unsigned v;
    asm volatile("global_atomic_add %0, %1, %2, off sc0\n\t"
                 "s_waitcnt vmcnt(0)"
                 : "=&v"(v) : "v"(p), "v"(0u) : "memory");
    return v;
}
__device__ __forceinline__ float l2_get_f32(void* p) {
    return __uint_as_float(l2_get_u32(p));
}
__device__ __forceinline__ unsigned long long pack2(float a, float b) {
    return (unsigned long long)__float_as_uint(a) |
           ((unsigned long long)__float_as_uint(b) << 32);
}

// Persistent directional scan with point-to-point halo exchange.
// Block = all 64 channels x T cols. Carry row lives in LDS across steps; only
// 4-col halos cross blocks. Mapping: b=blk&7 (batch==XCD under round-robin),
// tile=blk>>3, chain neighbors at blk+-8. Link scope chosen at runtime from
// measured XCC ids: same-XCD -> L2 atomics, else IC atomics (always correct).
template <int T>
__global__ __launch_bounds__(256, 1) void scan_halo_kernel(
    float* __restrict__ buf, const float* __restrict__ w,
    const float* __restrict__ bias, const int N,
    const long long rowStride, const long long colStride,
    const long long chanStride, const int startRow, const int rowDir,
    const int numSteps, unsigned* __restrict__ flags,
    float* __restrict__ halo, unsigned* __restrict__ xccmap)
{
    constexpr int CPT = T / 4;   // output cols per thread
    constexpr int WIN = T + 8;   // staged window per ci
    constexpr int NB = 8;        // neighbor stride in blockIdx
    __shared__ float prev[C_][WIN];
    __shared__ unsigned s_ic[2];

    const int tid = threadIdx.x;
    const int co = tid >> 2;
    const int g = tid & 3;
    const int TPB = N / T;       // 32 for both variants
    const int blk = blockIdx.x;
    const int b = blk & 7;
    const int tile = blk >> 3;
    const int t0 = tile * T;
    const bool hasL = tile > 0;
    const bool hasR = tile < TPB - 1;

    // ---- one-time link-scope discovery ----
    bool icL = hasL, icR = hasR;  // default IC (also covers flags==nullptr)
    if (flags != nullptr) {
        if (tid == 0) {
            const unsigned my = xcc_id();
            __hip_atomic_store(xccmap + blk, 0x100u | my, __ATOMIC_RELAXED,
                               __HIP_MEMORY_SCOPE_AGENT);
            unsigned xl = 0, xr = 0;
            if (hasL)
                while (!((xl = __hip_atomic_load(xccmap + blk - NB,
                                                 __ATOMIC_RELAXED,
                                                 __HIP_MEMORY_SCOPE_AGENT)) &
                         0x100u))
                    __builtin_amdgcn_s_sleep(1);
            if (hasR)
                while (!((xr = __hip_atomic_load(xccmap + blk + NB,
                                                 __ATOMIC_RELAXED,
                                                 __HIP_MEMORY_SCOPE_AGENT)) &
                         0x100u))
                    __builtin_amdgcn_s_sleep(1);
            s_ic[0] = (hasL && ((xl & 0xffu) != my)) ? 1u : 0u;
            s_ic[1] = (hasR && ((xr & 0xffu) != my)) ? 1u : 0u;
        }
        __syncthreads();
        icL = s_ic[0] != 0;
        icR = s_ic[1] != 0;
    }

    const long long base = (long long)b * C_ * chanStride;

    // one-time: weights w[co][ci=g+4i][k] -> 144 VGPRs (resident: bounds(256,1))
    float wreg[16][K_];
    {
        const float* wb = w + (long long)co * C_ * K_;
#pragma unroll
        for (int i = 0; i < 16; ++i)
#pragma unroll
            for (int k = 0; k < K_; ++k)
                wreg[i][k] = wb[(g + 4 * i) * K_ + k];
    }
    const float bco = bias[co];

    for (int s = 0; s < numSteps; ++s) {
        const int irow = startRow + s * rowDir;

        if (s == 0) {
            // stage carry row from global (prev direction's output, incl halo)
            const long long pr = base + (long long)(irow - rowDir) * rowStride;
            for (int idx = tid; idx < C_ * WIN; idx += 256) {
                const int ci = idx / WIN, j = idx - ci * WIN;
                const int gc = t0 + j - PAD_;
                float v = 0.f;
                if (gc >= 0 && gc < N)
                    v = buf[pr + (long long)ci * chanStride +
                            (long long)gc * colStride];
                prev[ci][j] = v;
            }
        } else {
            // wait for neighbors' step s-1 (two waves spin in parallel)
            if (tid == 0 && hasL) {
                unsigned* fp = (unsigned*)((char*)flags + (blk - NB) * 128) +
                               (icL ? 16 : 0);
                if (icL) {
                    while (__hip_atomic_load(fp, __ATOMIC_RELAXED,
                                             __HIP_MEMORY_SCOPE_AGENT) <
                           (unsigned)s)
                        __builtin_amdgcn_s_sleep(1);
                } else {
                    while (l2_get_u32(fp) < (unsigned)s)
                        __builtin_amdgcn_s_sleep(1);
                }
            }
            if (tid == 64 && hasR) {
                unsigned* fp = (unsigned*)((char*)flags + (blk + NB) * 128) +
                               (icR ? 16 : 0);
                if (icR) {
                    while (__hip_atomic_load(fp, __ATOMIC_RELAXED,
                                             __HIP_MEMORY_SCOPE_AGENT) <
                           (unsigned)s)
                        __builtin_amdgcn_s_sleep(1);
                } else {
                    while (l2_get_u32(fp) < (unsigned)s)
                        __builtin_amdgcn_s_sleep(1);
                }
            }
            __syncthreads();
            // import halos (thread t -> ci = t>>2, c = t&3)
            const int par = (s - 1) & 1;
            float lv = 0.f, rv = 0.f;
            if (hasL) {
                float* p = halo + (((blk - NB) * 2 + par) * 2 + 1) * 256 + tid;
                lv = icL ? ic_load_f32(p) : l2_get_f32(p);
            }
            if (hasR) {
                float* p = halo + (((blk + NB) * 2 + par) * 2 + 0) * 256 + tid;
                rv = icR ? ic_load_f32(p) : l2_get_f32(p);
            }
            prev[tid >> 2][tid & 3] = lv;
            prev[tid >> 2][T + 4 + (tid & 3)] = rv;
        }
        __syncthreads();

        // x (RMW input) — issue early, used after compute
        const long long orow = base + (long long)co * chanStride +
                               (long long)irow * rowStride;
        const int colL = t0 + g * CPT;
        float xv[CPT];
        if (colStride == 1) {
            if constexpr (CPT == 4) {
                const float4 v4 = *(const float4*)(buf + orow + colL);
                xv[0] = v4.x; xv[1] = v4.y; xv[2] = v4.z; xv[3] = v4.w;
            } else {
                const float2 v2 = *(const float2*)(buf + orow + colL);
                xv[0] = v2.x; xv[1] = v2.y;
            }
        } else {
#pragma unroll
            for (int cc = 0; cc < CPT; ++cc)
                xv[cc] = buf[orow + (long long)(colL + cc) * colStride];
        }

        // partial conv over my ci-quarter, all T cols
        float acc[T];
#pragma unroll
        for (int c = 0; c < T; ++c) acc[c] = 0.f;
#pragma unroll
        for (int i = 0; i < 16; ++i) {
            const int ci = g + 4 * i;
            float win[WIN];
            const float4* rp = (const float4*)(&prev[ci][0]);
#pragma unroll
            for (int j = 0; j < WIN / 4; ++j) {
                const float4 v = rp[j];
                win[4 * j + 0] = v.x; win[4 * j + 1] = v.y;
                win[4 * j + 2] = v.z; win[4 * j + 3] = v.w;
            }
#pragma unroll
            for (int k = 0; k < K_; ++k)
#pragma unroll
                for (int c = 0; c < T; ++c)
                    acc[c] = fmaf(wreg[i][k], win[c + k], acc[c]);
        }
        // butterfly over g (lane bits 0-1)
#pragma unroll
        for (int c = 0; c < T; ++c) acc[c] += __shfl_xor(acc[c], 1);
#pragma unroll
        for (int c = 0; c < T; ++c) acc[c] += __shfl_xor(acc[c], 2);

        float r[CPT];
#pragma unroll
        for (int cc = 0; cc < CPT; ++cc)
            r[cc] = xv[cc] + fmaxf(acc[g * CPT + cc] + bco, 0.f);

        // store output row (plain cached; only this block re-reads these cols)
        if (colStride == 1) {
            if constexpr (CPT == 4) {
                const float4 v4 = {r[0], r[1], r[2], r[3]};
                *(float4*)(buf + orow + colL) = v4;
            } else {
                const float2 v2 = {r[0], r[1]};
                *(float2*)(buf + orow + colL) = v2;
            }
        } else {
#pragma unroll
            for (int cc = 0; cc < CPT; ++cc)
                buf[orow + (long long)(colL + cc) * colStride] = r[cc];
        }

        if (s != numSteps - 1 && flags != nullptr) {
            const int par = s & 1;
            // export edge cols (b64-packed), per-link scope
            if constexpr (CPT == 2) {
                const int side = g >> 1;              // 0:left 1:right
                const bool has = side ? hasR : hasL;
                if (has) {
                    const bool ic = side ? icR : icL;
                    float* p = halo + ((blk * 2 + par) * 2 + side) * 256 +
                               co * 4 + (g & 1) * 2;
                    const unsigned long long pk = pack2(r[0], r[1]);
                    if (ic)
                        (void)__hip_atomic_exchange((unsigned long long*)p, pk,
                                                    __ATOMIC_RELAXED,
                                                    __HIP_MEMORY_SCOPE_AGENT);
                    else
                        l2_put_u64(p, pk);
                }
            } else {  // CPT == 4: g==0 owns full left edge, g==3 full right
                if ((g == 0 && hasL) || (g == 3 && hasR)) {
                    const int side = (g == 0) ? 0 : 1;
                    const bool ic = side ? icR : icL;
                    float* p = halo + ((blk * 2 + par) * 2 + side) * 256 +
                               co * 4;
                    const unsigned long long p0 = pack2(r[0], r[1]);
                    const unsigned long long p1 = pack2(r[2], r[3]);
                    if (ic) {
                        (void)__hip_atomic_exchange((unsigned long long*)p, p0,
                                                    __ATOMIC_RELAXED,
                                                    __HIP_MEMORY_SCOPE_AGENT);
                        (void)__hip_atomic_exchange(
                            (unsigned long long*)(p + 2), p1, __ATOMIC_RELAXED,
                            __HIP_MEMORY_SCOPE_AGENT);
                    } else {
                        l2_put_u64(p, p0);
                        l2_put_u64(p + 2, p1);
                    }
                }
            }
            __syncthreads();  // everyone done READING prev
            // own outputs become next step's carry (interior cols)
#pragma unroll
            for (int cc = 0; cc < CPT; ++cc)
                prev[co][4 + g * CPT + cc] = r[cc];
            asm volatile("s_waitcnt vmcnt(0)" ::: "memory");  // exports landed
            __syncthreads();
            if (tid == 0) {
                const unsigned val = (unsigned)(s + 1);
                unsigned* fb = (unsigned*)((char*)flags + blk * 128);
                if ((hasL && !icL) || (hasR && !icR)) l2_put_u32(fb, val);
                if ((hasL && icL) || (hasR && icR))
                    __hip_atomic_store(fb + 16, val, __ATOMIC_RELAXED,
                                       __HIP_MEMORY_SCOPE_AGENT);
            }
        }
    }
}

// out[b,c,s,r] = in[b,c,r,s] for each of the B*C planes.
__global__ __launch_bounds__(256) void transpose_kernel(
    const float* __restrict__ in, float* __restrict__ out,
    const int R, const int S)
{
    __shared__ float tile[32][33];
    const size_t plane = (size_t)blockIdx.z * R * S;
    const int s0 = blockIdx.x * 32;
    const int r0 = blockIdx.y * 32;
    const int tx = threadIdx.x;
    const int ty = threadIdx.y;
#pragma unroll
    for (int j = 0; j < 32; j += 8)
        tile[ty + j][tx] = in[plane + (size_t)(r0 + ty + j) * S + s0 + tx];
    __syncthreads();
#pragma unroll
    for (int j = 0; j < 32; j += 8)
        out[plane + (size_t)(s0 + ty + j) * R + r0 + tx] = tile[tx][ty + j];
}

template <int T>
static void launch_dir(float* buf, const float* w, const float* bias, int N,
                       long long rowStride, long long colStride,
                       long long chanStride, int startRow, int rowDir,
                       int numSteps, unsigned* flags, float* halo,
                       unsigned* xccmap, bool persistent, hipStream_t stream)
{
    const int nblocks = 8 * (N / T);   // == 256
    if (persistent) {
        scan_halo_kernel<T><<<nblocks, 256, 0, stream>>>(
            buf, w, bias, N, rowStride, colStride, chanStride, startRow,
            rowDir, numSteps, flags, halo, xccmap);
    } else {
        for (int s = 0; s < numSteps; ++s)
            scan_halo_kernel<T><<<nblocks, 256, 0, stream>>>(
                buf, w, bias, N, rowStride, colStride, chanStride,
                startRow + s * rowDir, rowDir, 1, nullptr, nullptr, nullptr);
    }
}

extern "C" void kernel_launch(void* const* d_in, const int* in_sizes, int n_in,
                              void* d_out, int out_size, void* d_ws,
                              size_t ws_size, hipStream_t stream)
{
    const float* x    = (const float*)d_in[0];
    const float* w_ud = (const float*)d_in[1];
    const float* b_ud = (const float*)d_in[2];
    const float* w_du = (const float*)d_in[3];
    const float* b_du = (const float*)d_in[4];
    const float* w_lr = (const float*)d_in[5];
    const float* b_lr = (const float*)d_in[6];
    const float* w_rl = (const float*)d_in[7];
    const float* b_rl = (const float*)d_in[8];
    float* out = (float*)d_out;

    const size_t total = (size_t)B_ * C_ * H_ * W_;
    const long long chan = (long long)H_ * W_;

    const bool haveSync = ws_size >= HALO_OFF + 4 * HALO_PER_DIR;
    const bool haveT = ws_size >= TBUF_OFF + total * sizeof(float);

    float* wsT = (float*)((char*)d_ws + TBUF_OFF);

    hipMemcpyAsync(out, x, total * sizeof(float), hipMemcpyDeviceToDevice,
                   stream);
    if (haveSync) hipMemsetAsync(d_ws, 0, INIT_BYTES, stream);

    unsigned* fl[4];
    float* hl[4];
    unsigned* xm[4];
    for (int d = 0; d < 4; ++d) {
        fl[d] = (unsigned*)((char*)d_ws + FLAGS_OFF + d * FLAGS_PER_DIR);
        hl[d] = (float*)((char*)d_ws + HALO_OFF + d * HALO_PER_DIR);
        xm[d] = (unsigned*)((char*)d_ws + XCC_OFF + d * XCC_PER_DIR);
    }

    // up->down / down->up on [b,c,h,w]: scan h, conv along w (contig, N=512)
    launch_dir<16>(out, w_ud, b_ud, W_, (long long)W_, 1LL, chan,
                   1, +1, H_ - 1, fl[0], hl[0], xm[0], haveSync, stream);
    launch_dir<16>(out, w_du, b_du, W_, (long long)W_, 1LL, chan,
                   H_ - 2, -1, H_ - 1, fl[1], hl[1], xm[1], haveSync, stream);

    if (haveT) {
        // transpose to [b,c,w,h]: scan w, conv along h (contig, N=256)
        {
            dim3 gt(W_ / 32, H_ / 32, B_ * C_);
            transpose_kernel<<<gt, dim3(32, 8), 0, stream>>>(out, wsT, H_, W_);
        }
        launch_dir<8>(wsT, w_lr, b_lr, H_, (long long)H_, 1LL, chan,
                      1, +1, W_ - 1, fl[2], hl[2], xm[2], haveSync, stream);
        launch_dir<8>(wsT, w_rl, b_rl, H_, (long long)H_, 1LL, chan,
                      W_ - 2, -1, W_ - 1, fl[3], hl[3], xm[3], haveSync,
                      stream);
        {
            dim3 gt(H_ / 32, W_ / 32, B_ * C_);
            transpose_kernel<<<gt, dim3(32, 8), 0, stream>>>(wsT, out, W_, H_);
        }
    } else {
        // strided fallback on [b,c,h,w]: scan w (rowStride=1), conv along h
        launch_dir<8>(out, w_lr, b_lr, H_, 1LL, (long long)W_, chan,
                      1, +1, W_ - 1, fl[2], hl[2], xm[2], haveSync, stream);
        launch_dir<8>(out, w_rl, b_rl, H_, 1LL, (long long)W_, chan,
                      W_ - 2, -1, W_ - 1, fl[3], hl[3], xm[3], haveSync,
                      stream);
    }
}